// Round 1
// 326.810 us; speedup vs baseline: 1.0313x; 1.0313x over previous
//
#include <hip/hip_runtime.h>
#include <hip/hip_bf16.h>
#include <math.h>

typedef short s16x8 __attribute__((ext_vector_type(8)));
typedef float f32x4 __attribute__((ext_vector_type(4)));

#define B_ 4
#define S_ 2048
#define D_ 1024
#define H_ 16
#define HD_ 64
#define NT_ 16   // K tiles of 64 (D_/64)

__device__ __forceinline__ unsigned short f2bf(float f) {
    unsigned u = __float_as_uint(f);
    u += 0x7fffu + ((u >> 16) & 1u);   // round-to-nearest-even
    return (unsigned short)(u >> 16);
}
__device__ __forceinline__ float bf2f(unsigned short u) {
    return __uint_as_float(((unsigned)u) << 16);
}

// ---------------- single fused fp32 -> bf16 convert ----------------
__global__ void cvt_all(const float* __restrict__ q, const float* __restrict__ k,
                        const float* __restrict__ v, const float* __restrict__ wq,
                        const float* __restrict__ wk, const float* __restrict__ wv,
                        const float* __restrict__ wo,
                        unsigned short* __restrict__ oq, unsigned short* __restrict__ ok,
                        unsigned short* __restrict__ ov, unsigned short* __restrict__ owq,
                        unsigned short* __restrict__ owk, unsigned short* __restrict__ owv,
                        unsigned short* __restrict__ owo) {
    int i = blockIdx.x * 256 + threadIdx.x;
    const float* src; unsigned short* dst; int idx;
    if (i < 3 * (1 << 21)) {
        int w = i >> 21; idx = i & ((1 << 21) - 1);
        src = (w == 0) ? q : (w == 1) ? k : v;
        dst = (w == 0) ? oq : (w == 1) ? ok : ov;
    } else {
        int j = i - 3 * (1 << 21);
        int w = j >> 18; idx = j & ((1 << 18) - 1);
        src = (w == 0) ? wq : (w == 1) ? wk : (w == 2) ? wv : wo;
        dst = (w == 0) ? owq : (w == 1) ? owk : (w == 2) ? owv : owo;
    }
    float4 f = ((const float4*)src)[idx];
    ushort4 o;
    o.x = f2bf(f.x); o.y = f2bf(f.y); o.z = f2bf(f.z); o.w = f2bf(f.w);
    ((ushort4*)dst)[idx] = o;
}

// ====================================================================
// 8-phase-style deep-pipelined GEMM core: 256x128 tile, BK=64, 8 waves.
// - LDS per buffer: A half0 [0,16K) A half1 [16K,32K) B [32K,48K); dbuf at +48K. 96 KB total.
// - XOR bank swizzle: 16B granule g stored at g ^ (row&7); applied on the
//   global SOURCE address (global_load_lds writes linearly) and on ds_read.
// - Counted vmcnt(2) gate once per K-tile (never 0 in steady state); raw
//   s_barrier (no compiler vmcnt(0) drain); setprio(1) around MFMA clusters.
// - Per-tile stage plan: ph1: A-h1(t+1)->nxt; ph2: B(t+1)->nxt; ph4: A-h0(t+2)->cur
//   (cur's LDS reads all complete by end of ph3, so ph4's overwrite of A-h0 is WAR-safe).
// ====================================================================
__device__ __forceinline__ void gemm_core_8ph(
    const unsigned short* __restrict__ A,
    const unsigned short* __restrict__ Wt,
    int tm, int tn, f32x4 (&acc)[4][4]) {
    extern __shared__ char smem[];
    const int tid  = threadIdx.x;
    const int wave = tid >> 6, lane = tid & 63;
    const int quad = lane >> 4, low = lane & 15;
    const int wm   = (wave >> 1) * 64;     // 0,64,128,192
    const int wn   = (wave & 1) * 64;      // 0,64

    // staging geometry: thread covers stored bytes [tid*16,+16) per call
    const int srow = tid >> 3;                               // 0..63 (+64 on call 1)
    const int scol = ((tid & 7) ^ (srow & 7)) * 8;           // inverse swizzle on source
    const unsigned short* gA = A  + (size_t)(tm * 256 + srow) * D_ + scol;
    const unsigned short* gB = Wt + (size_t)(tn * 128 + srow) * D_ + scol;

    // ds_read geometry (swizzled)
    const int abase = ((wm >> 7) << 14) + ((wm & 127) + low) * 128;
    const int bbase = 32768 + (wn + low) * 128;
    const int g0 = (quad ^ (low & 7)) << 4;          // kk=0 granule byte offset
    const int g1 = ((4 + quad) ^ (low & 7)) << 4;    // kk=1

    auto stageA = [&](int t, int h, int poff) {
        const unsigned short* s0 = gA + (size_t)h * 128 * D_ + (size_t)t * 64;
        char* d0 = smem + poff + h * 16384 + wave * 1024;
        __builtin_amdgcn_global_load_lds(
            (const __attribute__((address_space(1))) void*)s0,
            (__attribute__((address_space(3))) void*)d0, 16, 0, 0);
        __builtin_amdgcn_global_load_lds(
            (const __attribute__((address_space(1))) void*)(s0 + (size_t)64 * D_),
            (__attribute__((address_space(3))) void*)(d0 + 8192), 16, 0, 0);
    };
    auto stageB = [&](int t, int poff) {
        const unsigned short* s0 = gB + (size_t)t * 64;
        char* d0 = smem + poff + 32768 + wave * 1024;
        __builtin_amdgcn_global_load_lds(
            (const __attribute__((address_space(1))) void*)s0,
            (__attribute__((address_space(3))) void*)d0, 16, 0, 0);
        __builtin_amdgcn_global_load_lds(
            (const __attribute__((address_space(1))) void*)(s0 + (size_t)64 * D_),
            (__attribute__((address_space(3))) void*)(d0 + 8192), 16, 0, 0);
    };
    auto ldA = [&](int mh, int blk, int kk, int poff) -> s16x8 {
        return *(const s16x8*)(smem + poff + abase + mh * 4096 + blk * 2048 + (kk ? g1 : g0));
    };
    auto ldB = [&](int nh, int nblk, int kk, int poff) -> s16x8 {
        return *(const s16x8*)(smem + poff + bbase + nh * 4096 + nblk * 2048 + (kk ? g1 : g0));
    };

    const f32x4 zf = {0.f, 0.f, 0.f, 0.f};
#pragma unroll
    for (int i = 0; i < 4; i++)
#pragma unroll
        for (int j = 0; j < 4; j++) acc[i][j] = zf;

    // prologue: A0(0),A1(0),B(0),A0(1) issued; oldest 6 must land (tile 0 complete)
    stageA(0, 0, 0);
    stageA(0, 1, 0);
    stageB(0, 0);
    stageA(1, 0, 49152);
    asm volatile("s_waitcnt vmcnt(2)" ::: "memory");
    __builtin_amdgcn_s_barrier();

    s16x8 af[2][2], b0f[2][2], b1f[2][2];
    auto MFMA8 = [&](int mh, int nh, s16x8 (&a)[2][2], s16x8 (&bb)[2][2]) {
#pragma unroll
        for (int blk = 0; blk < 2; blk++)
#pragma unroll
            for (int nblk = 0; nblk < 2; nblk++)
#pragma unroll
                for (int kk = 0; kk < 2; kk++)
                    acc[mh * 2 + blk][nh * 2 + nblk] =
                        __builtin_amdgcn_mfma_f32_16x16x32_bf16(
                            a[blk][kk], bb[nblk][kk], acc[mh * 2 + blk][nh * 2 + nblk], 0, 0, 0);
    };

    auto tile_step = [&](int t, int poff, int npoff) {
        // ---- phase 1: Q00 (A-mh0, B-nh0) ----
#pragma unroll
        for (int blk = 0; blk < 2; blk++)
#pragma unroll
            for (int kk = 0; kk < 2; kk++) af[blk][kk] = ldA(0, blk, kk, poff);
#pragma unroll
        for (int nblk = 0; nblk < 2; nblk++)
#pragma unroll
            for (int kk = 0; kk < 2; kk++) b0f[nblk][kk] = ldB(0, nblk, kk, poff);
        if (t + 1 < NT_) stageA(t + 1, 1, npoff);
        __builtin_amdgcn_s_barrier();
        asm volatile("s_waitcnt lgkmcnt(0)" ::: "memory");
        __builtin_amdgcn_sched_barrier(0);
        __builtin_amdgcn_s_setprio(1);
        MFMA8(0, 0, af, b0f);
        __builtin_amdgcn_s_setprio(0);
        __builtin_amdgcn_s_barrier();
        // ---- phase 2: Q01 (B-nh1) ----
#pragma unroll
        for (int nblk = 0; nblk < 2; nblk++)
#pragma unroll
            for (int kk = 0; kk < 2; kk++) b1f[nblk][kk] = ldB(1, nblk, kk, poff);
        if (t + 1 < NT_) stageB(t + 1, npoff);
        __builtin_amdgcn_s_barrier();
        asm volatile("s_waitcnt lgkmcnt(0)" ::: "memory");
        __builtin_amdgcn_sched_barrier(0);
        __builtin_amdgcn_s_setprio(1);
        MFMA8(0, 1, af, b1f);
        __builtin_amdgcn_s_setprio(0);
        __builtin_amdgcn_s_barrier();
        // ---- phase 3: Q10 (A-mh1; last LDS reads of this buffer) ----
#pragma unroll
        for (int blk = 0; blk < 2; blk++)
#pragma unroll
            for (int kk = 0; kk < 2; kk++) af[blk][kk] = ldA(1, blk, kk, poff);
        __builtin_amdgcn_s_barrier();
        asm volatile("s_waitcnt lgkmcnt(0)" ::: "memory");
        __builtin_amdgcn_sched_barrier(0);
        __builtin_amdgcn_s_setprio(1);
        MFMA8(1, 0, af, b0f);
        __builtin_amdgcn_s_setprio(0);
        __builtin_amdgcn_s_barrier();
        // ---- phase 4: Q11 (no LDS reads) + gate for tile t+1 ----
        if (t + 2 < NT_) {
            stageA(t + 2, 0, poff);                       // WAR-safe: poff reads done ph3
            asm volatile("s_waitcnt vmcnt(2)" ::: "memory");  // oldest 6 = all of tile t+1
        } else if (t + 1 < NT_) {
            asm volatile("s_waitcnt vmcnt(0)" ::: "memory");  // tail: drain
        }
        __builtin_amdgcn_s_barrier();
        __builtin_amdgcn_s_setprio(1);
        MFMA8(1, 1, af, b1f);
        __builtin_amdgcn_s_setprio(0);
        __builtin_amdgcn_s_barrier();
    };

    for (int tt = 0; tt < NT_; tt += 2) {
        tile_step(tt,     0,     49152);
        tile_step(tt + 1, 49152, 0);
    }
}

// ---------------- merged QKV projection GEMM (bf16 out, head-split) ----------------
// XCD swizzle: blocks sharing (seg,tm) all have bid&7 == tm&7 -> same XCD slot,
// so each 512 KB A-strip is fetched once per XCD L2.
__global__ __launch_bounds__(512)
void gemm_qkv8(const unsigned short* __restrict__ qb, const unsigned short* __restrict__ kb,
               const unsigned short* __restrict__ vb,
               const unsigned short* __restrict__ Wqb, const unsigned short* __restrict__ Wkb,
               const unsigned short* __restrict__ Wvb,
               unsigned short* __restrict__ qhp, unsigned short* __restrict__ khp,
               unsigned short* __restrict__ vhTp) {
    const int c_  = blockIdx.x & 7;
    const int r_  = blockIdx.x >> 3;        // 0..95
    const int seg = r_ >> 5;                // 0..2
    const int j_  = r_ & 31;
    const int tn  = j_ & 7;                 // 0..7  (N/128)
    const int tm  = (j_ >> 3) * 8 + c_;     // 0..31 (M/256)
    const unsigned short* A = (seg == 0) ? qb  : (seg == 1) ? kb  : vb;
    const unsigned short* W = (seg == 0) ? Wqb : (seg == 1) ? Wkb : Wvb;
    unsigned short* Out     = (seg == 0) ? qhp : (seg == 1) ? khp : vhTp;
    const float oscale      = (seg == 0) ? 0.125f : 1.0f;
    const bool  vmode       = (seg == 2);

    f32x4 acc[4][4];
    gemm_core_8ph(A, W, tm, tn, acc);

    const int tid  = threadIdx.x;
    const int wave = tid >> 6, lane = tid & 63;
    const int quad = lane >> 4, low = lane & 15;
    const int wm   = (wave >> 1) * 64, wn = (wave & 1) * 64;
#pragma unroll
    for (int i = 0; i < 4; i++) {
#pragma unroll
        for (int j = 0; j < 4; j++) {
#pragma unroll
            for (int r = 0; r < 4; r++) {
                int m = tm * 256 + wm + i * 16 + quad * 4 + r;
                int n = tn * 128 + wn + j * 16 + low;
                float val = acc[i][j][r] * oscale;
                int b = m >> 11, l = m & 2047;
                int h = n >> 6,  d = n & 63;
                size_t idx = vmode
                    ? ((size_t)(b * H_ + h) * HD_ + d) * S_ + l
                    : ((size_t)(b * H_ + h) * S_ + l) * HD_ + d;
                Out[idx] = f2bf(val);
            }
        }
    }
}

// ---------------- output projection GEMM (fp32 + bias) ----------------
__global__ __launch_bounds__(512)
void gemm_wo8(const unsigned short* __restrict__ A, const unsigned short* __restrict__ W,
              float* __restrict__ Out, const float* __restrict__ bias) {
    const int c_ = blockIdx.x & 7;
    const int j_ = blockIdx.x >> 3;         // 0..31
    const int tn = j_ & 7;
    const int tm = (j_ >> 3) * 8 + c_;

    f32x4 acc[4][4];
    gemm_core_8ph(A, W, tm, tn, acc);

    const int tid  = threadIdx.x;
    const int wave = tid >> 6, lane = tid & 63;
    const int quad = lane >> 4, low = lane & 15;
    const int wm   = (wave >> 1) * 64, wn = (wave & 1) * 64;
#pragma unroll
    for (int i = 0; i < 4; i++) {
#pragma unroll
        for (int j = 0; j < 4; j++) {
#pragma unroll
            for (int r = 0; r < 4; r++) {
                int m = tm * 256 + wm + i * 16 + quad * 4 + r;
                int n = tn * 128 + wn + j * 16 + low;
                Out[(size_t)m * D_ + n] = acc[i][j][r] + bias[n];
            }
        }
    }
}

// ---------------- V suffix sums over 64-chunk boundaries ----------------
__global__ __launch_bounds__(256)
void vsuffix_kernel(const unsigned short* __restrict__ vhT, float* __restrict__ vsuf) {
    const int tid  = threadIdx.x;
    const int wave = tid >> 6, lane = tid & 63;
    const int row  = blockIdx.x * 4 + wave;          // 0..4095 = bh*64 + d
    const int bh   = row >> 6, d = row & 63;
    const unsigned short* src = vhT + ((size_t)bh * HD_ + d) * S_ + lane * 32;
    float p = 0.f;
#pragma unroll
    for (int c = 0; c < 4; c++) {
        s16x8 v = *(const s16x8*)(src + c * 8);
#pragma unroll
        for (int e = 0; e < 8; e++) p += bf2f((unsigned short)v[e]);
    }
    __shared__ float ps[4][64];
    ps[wave][lane] = p;                               // wave-synchronous
    if (lane >= 1 && lane <= 32) {
        float s = 0.f;
        for (int l = lane * 2; l < 64; l++) s += ps[wave][l];
        vsuf[((size_t)bh * 33 + lane) * 64 + d] = s;  // lane=32 writes 0
    }
}

// ---------------- causal attention: 128-row Q tile, shared K/V staging ----------------
__global__ __launch_bounds__(256)
void attn_kernel(const unsigned short* __restrict__ qh,
                 const unsigned short* __restrict__ kh,
                 const unsigned short* __restrict__ vhT,
                 const float* __restrict__ vsuf,
                 unsigned short* __restrict__ ao) {
    const int bh = blockIdx.x & 63;           // same-bh at stride 64 (%8==0: XCD affinity)
    const int t  = 15 - (blockIdx.x >> 6);    // heaviest blocks dispatch first
    const int tA = 2 * t, tB = 2 * t + 1;
    const int l0A = tA * 64, l0B = tB * 64;
    const int b = bh >> 4, h = bh & 15;

    __shared__ unsigned short Ks[64][68];   // +4 pad, bank-balanced
    __shared__ unsigned short Vs[64][68];
    __shared__ unsigned short Ps[64][68];   // per-wave-private 16-row slices

    const int tid  = threadIdx.x;
    const int wave = tid >> 6, lane = tid & 63;
    const int quad = lane >> 4, low = lane & 15;
    const int lr   = tid >> 2;
    const int lc8  = (tid & 3);

    const size_t qbA = ((size_t)bh * S_ + l0A + wave * 16 + low) * HD_;
    const size_t qbB = ((size_t)bh * S_ + l0B + wave * 16 + low) * HD_;
    const s16x8 aqA0 = *(const s16x8*)(qh + qbA + quad * 8);
    const s16x8 aqA1 = *(const s16x8*)(qh + qbA + 32 + quad * 8);
    const s16x8 aqB0 = *(const s16x8*)(qh + qbB + quad * 8);
    const s16x8 aqB1 = *(const s16x8*)(qh + qbB + 32 + quad * 8);

    const s16x8 onesv = {0x3F80, 0x3F80, 0x3F80, 0x3F80,
                         0x3F80, 0x3F80, 0x3F80, 0x3F80};  // bf16 1.0 x8

    f32x4 accA[4], accB[4];
    const f32x4 zf = {0.f, 0.f, 0.f, 0.f};
#pragma unroll
    for (int n = 0; n < 4; n++) { accA[n] = zf; accB[n] = zf; }
    f32x4 sumA = zf, sumB = zf;

    const unsigned short* kptr = kh  + ((size_t)bh * S_) * HD_ + lr * HD_ + lc8 * 8;
    const unsigned short* vptr = vhT + ((size_t)bh * HD_) * S_ + (size_t)lr * S_ + lc8 * 8;

    // prefetch chunk 0
    int4 kc0 = *(const int4*)(kptr);
    int4 kc1 = *(const int4*)(kptr + 32);
    int4 vc0 = *(const int4*)(vptr);
    int4 vc1 = *(const int4*)(vptr + 32);

    const int lastc = tB;
    for (int c = 0; c <= lastc; ++c) {
        const int s0 = c * 64;
        __syncthreads();                 // prev chunk consumed; drains in-flight loads (overlapped)
        *(int4*)&Ks[lr][lc8 * 8]      = kc0;
        *(int4*)&Ks[lr][lc8 * 8 + 32] = kc1;
        *(int4*)&Vs[lr][lc8 * 8]      = vc0;
        *(int4*)&Vs[lr][lc8 * 8 + 32] = vc1;
        __syncthreads();                 // staging visible (lgkm-only drain: cheap)
        if (c < lastc) {                 // issue AFTER barrier -> in flight across compute
            const int off = (c + 1) * 64;
            kc0 = *(const int4*)(kptr + (size_t)off * HD_);
            kc1 = *(const int4*)(kptr + (size_t)off * HD_ + 32);
            vc0 = *(const int4*)(vptr + off);
            vc1 = *(const int4*)(vptr + off + 32);
        }

        auto tilework = [&](const s16x8& aq0, const s16x8& aq1, f32x4* acc, f32x4& sum,
                            int l0t, bool diag) {
            f32x4 sc[4];
#pragma unroll
            for (int j = 0; j < 4; j++) {
                s16x8 bk0 = *(const s16x8*)&Ks[j * 16 + low][quad * 8];
                s16x8 bk1 = *(const s16x8*)&Ks[j * 16 + low][32 + quad * 8];
                f32x4 cc = zf;
                cc = __builtin_amdgcn_mfma_f32_16x16x32_bf16(aq0, bk0, cc, 0, 0, 0);
                cc = __builtin_amdgcn_mfma_f32_16x16x32_bf16(aq1, bk1, cc, 0, 0, 0);
                sc[j] = cc;
            }
            float ee[4][4];
#pragma unroll
            for (int j = 0; j < 4; j++)
#pragma unroll
                for (int r = 0; r < 4; r++) ee[j][r] = __expf(sc[j][r]);
            if (diag) {
#pragma unroll
                for (int j = 0; j < 4; j++) {
                    const int sg = s0 + j * 16 + low;
#pragma unroll
                    for (int r = 0; r < 4; r++)
                        if (sg > l0t + wave * 16 + quad * 4 + r) ee[j][r] = 1.0f;
                }
            }
#pragma unroll
            for (int j = 0; j < 4; j++)
#pragma unroll
                for (int r = 0; r < 4; r++)
                    Ps[wave * 16 + quad * 4 + r][j * 16 + low] = f2bf(ee[j][r]);

            s16x8 pa0 = *(const s16x8*)&Ps[wave * 16 + low][quad * 8];
            s16x8 pa1 = *(const s16x8*)&Ps[wave * 16 + low][32 + quad * 8];
            sum = __builtin_amdgcn_mfma_f32_16x16x32_bf16(pa0, onesv, sum, 0, 0, 0);
            sum = __builtin_amdgcn_mfma_f32_16x16x32_bf16(pa1, onesv, sum, 0, 0, 0);
#pragma unroll
            for (int n = 0; n < 4; n++) {
                s16x8 bv0 = *(const s16x8*)&Vs[n * 16 + low][quad * 8];
                s16x8 bv1 = *(const s16x8*)&Vs[n * 16 + low][32 + quad * 8];
                acc[n] = __builtin_amdgcn_mfma_f32_16x16x32_bf16(pa0, bv0, acc[n], 0, 0, 0);
                acc[n] = __builtin_amdgcn_mfma_f32_16x16x32_bf16(pa1, bv1, acc[n], 0, 0, 0);
            }
        };

        tilework(aqB0, aqB1, accB, sumB, l0B, c == tB);
        if (c <= tA) tilework(aqA0, aqA1, accA, sumA, l0A, c == tA);
    }

    auto finalize = [&](f32x4* acc, f32x4 sum, int tt) {
        const float tail = (float)(S_ - 64 * (tt + 1));
        const float* sufp = vsuf + ((size_t)bh * 33 + tt + 1) * 64;
        float sv[4];
#pragma unroll
        for (int n = 0; n < 4; n++) sv[n] = sufp[n * 16 + low];
#pragma unroll
        for (int r = 0; r < 4; r++) {
            float inv = 1.0f / (sum[r] + tail);   // sum[r]: row quad*4+r (ones-MFMA)
            int lg = tt * 64 + wave * 16 + quad * 4 + r;
            size_t base = ((size_t)b * S_ + lg) * D_ + h * HD_;
#pragma unroll
            for (int n = 0; n < 4; n++)
                ao[base + n * 16 + low] = f2bf((acc[n][r] + sv[n]) * inv);
        }
    };
    finalize(accA, sumA, tA);
    finalize(accB, sumB, tB);
}

// ---------------- launch ----------------
extern "C" void kernel_launch(void* const* d_in, const int* in_sizes, int n_in,
                              void* d_out, int out_size, void* d_ws, size_t ws_size,
                              hipStream_t stream) {
    const float* q  = (const float*)d_in[0];
    const float* k  = (const float*)d_in[1];
    const float* v  = (const float*)d_in[2];
    const float* Wq = (const float*)d_in[4];
    const float* Wk = (const float*)d_in[5];
    const float* Wv = (const float*)d_in[6];
    const float* Wo = (const float*)d_in[7];
    const float* bo = (const float*)d_in[8];

    char* ws = (char*)d_ws;
    const size_t SZX = (size_t)B_ * S_ * D_ * 2;
    const size_t SZW = (size_t)D_ * D_ * 2;

    unsigned short* qb   = (unsigned short*)(ws);
    unsigned short* kb   = (unsigned short*)(ws + SZX);
    unsigned short* vb   = (unsigned short*)(ws + 2 * SZX);
    unsigned short* qhp  = (unsigned short*)(ws + 3 * SZX);
    unsigned short* khp  = (unsigned short*)(ws + 4 * SZX);
    unsigned short* vhTp = (unsigned short*)(ws + 5 * SZX);
    unsigned short* Wqb  = (unsigned short*)(ws + 6 * SZX);
    unsigned short* Wkb  = (unsigned short*)(ws + 6 * SZX + SZW);
    unsigned short* Wvb  = (unsigned short*)(ws + 6 * SZX + 2 * SZW);
    unsigned short* Wob  = (unsigned short*)(ws + 6 * SZX + 3 * SZW);
    unsigned short* aop  = qb;              // qb dead after Q projection
    float*          vsuf = (float*)vb;      // vb dead after V projection

    static bool s_init = false;
    if (!s_init) {
        hipFuncSetAttribute((const void*)gemm_qkv8,
                            hipFuncAttributeMaxDynamicSharedMemorySize, 98304);
        hipFuncSetAttribute((const void*)gemm_wo8,
                            hipFuncAttributeMaxDynamicSharedMemorySize, 98304);
        s_init = true;
    }

    cvt_all<<<(3 * (1 << 21) + 4 * (1 << 18)) / 256, 256, 0, stream>>>(
        q, k, v, Wq, Wk, Wv, Wo, qb, kb, vb, Wqb, Wkb, Wvb, Wob);

    gemm_qkv8<<<768, 512, 98304, stream>>>(qb, kb, vb, Wqb, Wkb, Wvb, qhp, khp, vhTp);

    vsuffix_kernel<<<1024, 256, 0, stream>>>(vhTp, vsuf);
    attn_kernel<<<1024, 256, 0, stream>>>(qhp, khp, vhTp, vsuf, aop);

    gemm_wo8<<<256, 512, 98304, stream>>>(aop, Wob, (float*)d_out, bo);
}

// Round 2
// 326.178 us; speedup vs baseline: 1.0333x; 1.0019x over previous
//
#include <hip/hip_runtime.h>
#include <hip/hip_bf16.h>
#include <math.h>

typedef short s16x8 __attribute__((ext_vector_type(8)));
typedef float f32x4 __attribute__((ext_vector_type(4)));

#define B_ 4
#define S_ 2048
#define D_ 1024
#define H_ 16
#define HD_ 64
#define NT_ 16   // K tiles of 64 (D_/64)

__device__ __forceinline__ unsigned short f2bf(float f) {
    unsigned u = __float_as_uint(f);
    u += 0x7fffu + ((u >> 16) & 1u);   // round-to-nearest-even
    return (unsigned short)(u >> 16);
}
__device__ __forceinline__ float bf2f(unsigned short u) {
    return __uint_as_float(((unsigned)u) << 16);
}

// ---------------- single fused fp32 -> bf16 convert ----------------
__global__ void cvt_all(const float* __restrict__ q, const float* __restrict__ k,
                        const float* __restrict__ v, const float* __restrict__ wq,
                        const float* __restrict__ wk, const float* __restrict__ wv,
                        const float* __restrict__ wo,
                        unsigned short* __restrict__ oq, unsigned short* __restrict__ ok,
                        unsigned short* __restrict__ ov, unsigned short* __restrict__ owq,
                        unsigned short* __restrict__ owk, unsigned short* __restrict__ owv,
                        unsigned short* __restrict__ owo) {
    int i = blockIdx.x * 256 + threadIdx.x;
    const float* src; unsigned short* dst; int idx;
    if (i < 3 * (1 << 21)) {
        int w = i >> 21; idx = i & ((1 << 21) - 1);
        src = (w == 0) ? q : (w == 1) ? k : v;
        dst = (w == 0) ? oq : (w == 1) ? ok : ov;
    } else {
        int j = i - 3 * (1 << 21);
        int w = j >> 18; idx = j & ((1 << 18) - 1);
        src = (w == 0) ? wq : (w == 1) ? wk : (w == 2) ? wv : wo;
        dst = (w == 0) ? owq : (w == 1) ? owk : (w == 2) ? owv : owo;
    }
    float4 f = ((const float4*)src)[idx];
    ushort4 o;
    o.x = f2bf(f.x); o.y = f2bf(f.y); o.z = f2bf(f.z); o.w = f2bf(f.w);
    ((ushort4*)dst)[idx] = o;
}

// ====================================================================
// 8-phase-style deep-pipelined GEMM core: 256x128 tile, BK=64, 8 waves.
// - LDS per buffer: A half0 [0,16K) A half1 [16K,32K) B [32K,48K); dbuf at +48K. 96 KB total.
// - XOR bank swizzle: 16B granule g stored at g ^ (row&7); applied on the
//   global SOURCE address (global_load_lds writes linearly) and on ds_read.
// - Counted vmcnt(2) gate once per K-tile (never 0 in steady state); raw
//   s_barrier (no compiler vmcnt(0) drain); setprio(1) around MFMA clusters.
// - Per-tile stage plan: ph1: A-h1(t+1)->nxt; ph2: B(t+1)->nxt; ph4: A-h0(t+2)->cur
//   (cur's LDS reads all complete by end of ph3, so ph4's overwrite of A-h0 is WAR-safe).
// ====================================================================
__device__ __forceinline__ void gemm_core_8ph(
    const unsigned short* __restrict__ A,
    const unsigned short* __restrict__ Wt,
    int tm, int tn, f32x4 (&acc)[4][4]) {
    extern __shared__ char smem[];
    const int tid  = threadIdx.x;
    const int wave = tid >> 6, lane = tid & 63;
    const int quad = lane >> 4, low = lane & 15;
    const int wm   = (wave >> 1) * 64;     // 0,64,128,192
    const int wn   = (wave & 1) * 64;      // 0,64

    // staging geometry: thread covers stored bytes [tid*16,+16) per call
    const int srow = tid >> 3;                               // 0..63 (+64 on call 1)
    const int scol = ((tid & 7) ^ (srow & 7)) * 8;           // inverse swizzle on source
    const unsigned short* gA = A  + (size_t)(tm * 256 + srow) * D_ + scol;
    const unsigned short* gB = Wt + (size_t)(tn * 128 + srow) * D_ + scol;

    // ds_read geometry (swizzled)
    const int abase = ((wm >> 7) << 14) + ((wm & 127) + low) * 128;
    const int bbase = 32768 + (wn + low) * 128;
    const int g0 = (quad ^ (low & 7)) << 4;          // kk=0 granule byte offset
    const int g1 = ((4 + quad) ^ (low & 7)) << 4;    // kk=1

    auto stageA = [&](int t, int h, int poff) {
        const unsigned short* s0 = gA + (size_t)h * 128 * D_ + (size_t)t * 64;
        char* d0 = smem + poff + h * 16384 + wave * 1024;
        __builtin_amdgcn_global_load_lds(
            (const __attribute__((address_space(1))) void*)s0,
            (__attribute__((address_space(3))) void*)d0, 16, 0, 0);
        __builtin_amdgcn_global_load_lds(
            (const __attribute__((address_space(1))) void*)(s0 + (size_t)64 * D_),
            (__attribute__((address_space(3))) void*)(d0 + 8192), 16, 0, 0);
    };
    auto stageB = [&](int t, int poff) {
        const unsigned short* s0 = gB + (size_t)t * 64;
        char* d0 = smem + poff + 32768 + wave * 1024;
        __builtin_amdgcn_global_load_lds(
            (const __attribute__((address_space(1))) void*)s0,
            (__attribute__((address_space(3))) void*)d0, 16, 0, 0);
        __builtin_amdgcn_global_load_lds(
            (const __attribute__((address_space(1))) void*)(s0 + (size_t)64 * D_),
            (__attribute__((address_space(3))) void*)(d0 + 8192), 16, 0, 0);
    };
    auto ldA = [&](int mh, int blk, int kk, int poff) -> s16x8 {
        return *(const s16x8*)(smem + poff + abase + mh * 4096 + blk * 2048 + (kk ? g1 : g0));
    };
    auto ldB = [&](int nh, int nblk, int kk, int poff) -> s16x8 {
        return *(const s16x8*)(smem + poff + bbase + nh * 4096 + nblk * 2048 + (kk ? g1 : g0));
    };

    const f32x4 zf = {0.f, 0.f, 0.f, 0.f};
#pragma unroll
    for (int i = 0; i < 4; i++)
#pragma unroll
        for (int j = 0; j < 4; j++) acc[i][j] = zf;

    // prologue: A0(0),A1(0),B(0),A0(1) issued; oldest 6 must land (tile 0 complete)
    stageA(0, 0, 0);
    stageA(0, 1, 0);
    stageB(0, 0);
    stageA(1, 0, 49152);
    asm volatile("s_waitcnt vmcnt(2)" ::: "memory");
    __builtin_amdgcn_s_barrier();

    s16x8 af[2][2], b0f[2][2], b1f[2][2];
    auto MFMA8 = [&](int mh, int nh, s16x8 (&a)[2][2], s16x8 (&bb)[2][2]) {
#pragma unroll
        for (int blk = 0; blk < 2; blk++)
#pragma unroll
            for (int nblk = 0; nblk < 2; nblk++)
#pragma unroll
                for (int kk = 0; kk < 2; kk++)
                    acc[mh * 2 + blk][nh * 2 + nblk] =
                        __builtin_amdgcn_mfma_f32_16x16x32_bf16(
                            a[blk][kk], bb[nblk][kk], acc[mh * 2 + blk][nh * 2 + nblk], 0, 0, 0);
    };

    auto tile_step = [&](int t, int poff, int npoff) {
        // ---- phase 1: Q00 (A-mh0, B-nh0) ----
#pragma unroll
        for (int blk = 0; blk < 2; blk++)
#pragma unroll
            for (int kk = 0; kk < 2; kk++) af[blk][kk] = ldA(0, blk, kk, poff);
#pragma unroll
        for (int nblk = 0; nblk < 2; nblk++)
#pragma unroll
            for (int kk = 0; kk < 2; kk++) b0f[nblk][kk] = ldB(0, nblk, kk, poff);
        if (t + 1 < NT_) stageA(t + 1, 1, npoff);
        __builtin_amdgcn_s_barrier();
        asm volatile("s_waitcnt lgkmcnt(0)" ::: "memory");
        __builtin_amdgcn_sched_barrier(0);
        __builtin_amdgcn_s_setprio(1);
        MFMA8(0, 0, af, b0f);
        __builtin_amdgcn_s_setprio(0);
        __builtin_amdgcn_s_barrier();
        // ---- phase 2: Q01 (B-nh1) ----
#pragma unroll
        for (int nblk = 0; nblk < 2; nblk++)
#pragma unroll
            for (int kk = 0; kk < 2; kk++) b1f[nblk][kk] = ldB(1, nblk, kk, poff);
        if (t + 1 < NT_) stageB(t + 1, npoff);
        __builtin_amdgcn_s_barrier();
        asm volatile("s_waitcnt lgkmcnt(0)" ::: "memory");
        __builtin_amdgcn_sched_barrier(0);
        __builtin_amdgcn_s_setprio(1);
        MFMA8(0, 1, af, b1f);
        __builtin_amdgcn_s_setprio(0);
        __builtin_amdgcn_s_barrier();
        // ---- phase 3: Q10 (A-mh1; last LDS reads of this buffer) ----
#pragma unroll
        for (int blk = 0; blk < 2; blk++)
#pragma unroll
            for (int kk = 0; kk < 2; kk++) af[blk][kk] = ldA(1, blk, kk, poff);
        __builtin_amdgcn_s_barrier();
        asm volatile("s_waitcnt lgkmcnt(0)" ::: "memory");
        __builtin_amdgcn_sched_barrier(0);
        __builtin_amdgcn_s_setprio(1);
        MFMA8(1, 0, af, b0f);
        __builtin_amdgcn_s_setprio(0);
        __builtin_amdgcn_s_barrier();
        // ---- phase 4: Q11 (no LDS reads) + gate for tile t+1 ----
        if (t + 2 < NT_) {
            stageA(t + 2, 0, poff);                       // WAR-safe: poff reads done ph3
            asm volatile("s_waitcnt vmcnt(2)" ::: "memory");  // oldest 6 = all of tile t+1
        } else if (t + 1 < NT_) {
            asm volatile("s_waitcnt vmcnt(0)" ::: "memory");  // tail: drain
        }
        __builtin_amdgcn_s_barrier();
        __builtin_amdgcn_s_setprio(1);
        MFMA8(1, 1, af, b1f);
        __builtin_amdgcn_s_setprio(0);
        __builtin_amdgcn_s_barrier();
    };

    for (int tt = 0; tt < NT_; tt += 2) {
        tile_step(tt,     0,     49152);
        tile_step(tt + 1, 49152, 0);
    }
}

// ---------------- merged QKV projection GEMM (bf16 out, head-split) ----------------
// XCD swizzle: blocks sharing (seg,tm) all have bid&7 == tm&7 -> same XCD slot,
// so each 512 KB A-strip is fetched once per XCD L2.
__global__ __launch_bounds__(512)
void gemm_qkv8(const unsigned short* __restrict__ qb, const unsigned short* __restrict__ kb,
               const unsigned short* __restrict__ vb,
               const unsigned short* __restrict__ Wqb, const unsigned short* __restrict__ Wkb,
               const unsigned short* __restrict__ Wvb,
               unsigned short* __restrict__ qhp, unsigned short* __restrict__ khp,
               unsigned short* __restrict__ vhTp) {
    const int c_  = blockIdx.x & 7;
    const int r_  = blockIdx.x >> 3;        // 0..95
    const int seg = r_ >> 5;                // 0..2
    const int j_  = r_ & 31;
    const int tn  = j_ & 7;                 // 0..7  (N/128)
    const int tm  = (j_ >> 3) * 8 + c_;     // 0..31 (M/256)
    const unsigned short* A = (seg == 0) ? qb  : (seg == 1) ? kb  : vb;
    const unsigned short* W = (seg == 0) ? Wqb : (seg == 1) ? Wkb : Wvb;
    unsigned short* Out     = (seg == 0) ? qhp : (seg == 1) ? khp : vhTp;
    const float oscale      = (seg == 0) ? 0.125f : 1.0f;
    const bool  vmode       = (seg == 2);

    f32x4 acc[4][4];
    gemm_core_8ph(A, W, tm, tn, acc);

    const int tid  = threadIdx.x;
    const int wave = tid >> 6, lane = tid & 63;
    const int quad = lane >> 4, low = lane & 15;
    const int wm   = (wave >> 1) * 64, wn = (wave & 1) * 64;
#pragma unroll
    for (int i = 0; i < 4; i++) {
#pragma unroll
        for (int j = 0; j < 4; j++) {
#pragma unroll
            for (int r = 0; r < 4; r++) {
                int m = tm * 256 + wm + i * 16 + quad * 4 + r;
                int n = tn * 128 + wn + j * 16 + low;
                float val = acc[i][j][r] * oscale;
                int b = m >> 11, l = m & 2047;
                int h = n >> 6,  d = n & 63;
                size_t idx = vmode
                    ? ((size_t)(b * H_ + h) * HD_ + d) * S_ + l
                    : ((size_t)(b * H_ + h) * S_ + l) * HD_ + d;
                Out[idx] = f2bf(val);
            }
        }
    }
}

// ---------------- output projection GEMM (fp32 + bias) ----------------
__global__ __launch_bounds__(512)
void gemm_wo8(const unsigned short* __restrict__ A, const unsigned short* __restrict__ W,
              float* __restrict__ Out, const float* __restrict__ bias) {
    const int c_ = blockIdx.x & 7;
    const int j_ = blockIdx.x >> 3;         // 0..31
    const int tn = j_ & 7;
    const int tm = (j_ >> 3) * 8 + c_;

    f32x4 acc[4][4];
    gemm_core_8ph(A, W, tm, tn, acc);

    const int tid  = threadIdx.x;
    const int wave = tid >> 6, lane = tid & 63;
    const int quad = lane >> 4, low = lane & 15;
    const int wm   = (wave >> 1) * 64, wn = (wave & 1) * 64;
#pragma unroll
    for (int i = 0; i < 4; i++) {
#pragma unroll
        for (int j = 0; j < 4; j++) {
#pragma unroll
            for (int r = 0; r < 4; r++) {
                int m = tm * 256 + wm + i * 16 + quad * 4 + r;
                int n = tn * 128 + wn + j * 16 + low;
                Out[(size_t)m * D_ + n] = acc[i][j][r] + bias[n];
            }
        }
    }
}

// ---------------- V suffix sums over 64-chunk boundaries ----------------
__global__ __launch_bounds__(256)
void vsuffix_kernel(const unsigned short* __restrict__ vhT, float* __restrict__ vsuf) {
    const int tid  = threadIdx.x;
    const int wave = tid >> 6, lane = tid & 63;
    const int row  = blockIdx.x * 4 + wave;          // 0..4095 = bh*64 + d
    const int bh   = row >> 6, d = row & 63;
    const unsigned short* src = vhT + ((size_t)bh * HD_ + d) * S_ + lane * 32;
    float p = 0.f;
#pragma unroll
    for (int c = 0; c < 4; c++) {
        s16x8 v = *(const s16x8*)(src + c * 8);
#pragma unroll
        for (int e = 0; e < 8; e++) p += bf2f((unsigned short)v[e]);
    }
    __shared__ float ps[4][64];
    ps[wave][lane] = p;                               // wave-synchronous
    if (lane >= 1 && lane <= 32) {
        float s = 0.f;
        for (int l = lane * 2; l < 64; l++) s += ps[wave][l];
        vsuf[((size_t)bh * 33 + lane) * 64 + d] = s;  // lane=32 writes 0
    }
}

// ---------------- causal attention: paired Q-tiles (p, 31-p) ----------------
// Tile-pairing balances work AND span exactly: block (bh,p) owns Q-tiles
// tA=p (light, active c<=tA) and tB=31-p (heavy, active all c<=tB).
// Per-wave serial span = (tA+1) + (tB+1) = 33 units for EVERY block
// (old (2t,2t+1) scheme spanned 4t+3 = 3..63 -> heaviest block gated the kernel).
__global__ __launch_bounds__(256)
void attn_kernel(const unsigned short* __restrict__ qh,
                 const unsigned short* __restrict__ kh,
                 const unsigned short* __restrict__ vhT,
                 const float* __restrict__ vsuf,
                 unsigned short* __restrict__ ao) {
    const int bh = blockIdx.x & 63;           // same-bh at stride 64 (%8==0: XCD affinity)
    const int p  = blockIdx.x >> 6;           // 0..15
    const int tA = p, tB = 31 - p;
    const int l0A = tA * 64, l0B = tB * 64;
    const int b = bh >> 4, h = bh & 15;

    __shared__ unsigned short Ks[64][68];   // +4 pad, bank-balanced
    __shared__ unsigned short Vs[64][68];
    __shared__ unsigned short Ps[64][68];   // per-wave-private 16-row slices

    const int tid  = threadIdx.x;
    const int wave = tid >> 6, lane = tid & 63;
    const int quad = lane >> 4, low = lane & 15;
    const int lr   = tid >> 2;
    const int lc8  = (tid & 3);

    const size_t qbA = ((size_t)bh * S_ + l0A + wave * 16 + low) * HD_;
    const size_t qbB = ((size_t)bh * S_ + l0B + wave * 16 + low) * HD_;
    const s16x8 aqA0 = *(const s16x8*)(qh + qbA + quad * 8);
    const s16x8 aqA1 = *(const s16x8*)(qh + qbA + 32 + quad * 8);
    const s16x8 aqB0 = *(const s16x8*)(qh + qbB + quad * 8);
    const s16x8 aqB1 = *(const s16x8*)(qh + qbB + 32 + quad * 8);

    const s16x8 onesv = {0x3F80, 0x3F80, 0x3F80, 0x3F80,
                         0x3F80, 0x3F80, 0x3F80, 0x3F80};  // bf16 1.0 x8

    f32x4 accA[4], accB[4];
    const f32x4 zf = {0.f, 0.f, 0.f, 0.f};
#pragma unroll
    for (int n = 0; n < 4; n++) { accA[n] = zf; accB[n] = zf; }
    f32x4 sumA = zf, sumB = zf;

    const unsigned short* kptr = kh  + ((size_t)bh * S_) * HD_ + lr * HD_ + lc8 * 8;
    const unsigned short* vptr = vhT + ((size_t)bh * HD_) * S_ + (size_t)lr * S_ + lc8 * 8;

    // prefetch chunk 0
    int4 kc0 = *(const int4*)(kptr);
    int4 kc1 = *(const int4*)(kptr + 32);
    int4 vc0 = *(const int4*)(vptr);
    int4 vc1 = *(const int4*)(vptr + 32);

    const int lastc = tB;
    for (int c = 0; c <= lastc; ++c) {
        const int s0 = c * 64;
        __syncthreads();                 // prev chunk consumed; drains in-flight loads (overlapped)
        *(int4*)&Ks[lr][lc8 * 8]      = kc0;
        *(int4*)&Ks[lr][lc8 * 8 + 32] = kc1;
        *(int4*)&Vs[lr][lc8 * 8]      = vc0;
        *(int4*)&Vs[lr][lc8 * 8 + 32] = vc1;
        __syncthreads();                 // staging visible (lgkm-only drain: cheap)
        if (c < lastc) {                 // issue AFTER barrier -> in flight across compute
            const int off = (c + 1) * 64;
            kc0 = *(const int4*)(kptr + (size_t)off * HD_);
            kc1 = *(const int4*)(kptr + (size_t)off * HD_ + 32);
            vc0 = *(const int4*)(vptr + off);
            vc1 = *(const int4*)(vptr + off + 32);
        }

        auto tilework = [&](const s16x8& aq0, const s16x8& aq1, f32x4* acc, f32x4& sum,
                            int l0t, bool diag) {
            f32x4 sc[4];
#pragma unroll
            for (int j = 0; j < 4; j++) {
                s16x8 bk0 = *(const s16x8*)&Ks[j * 16 + low][quad * 8];
                s16x8 bk1 = *(const s16x8*)&Ks[j * 16 + low][32 + quad * 8];
                f32x4 cc = zf;
                cc = __builtin_amdgcn_mfma_f32_16x16x32_bf16(aq0, bk0, cc, 0, 0, 0);
                cc = __builtin_amdgcn_mfma_f32_16x16x32_bf16(aq1, bk1, cc, 0, 0, 0);
                sc[j] = cc;
            }
            float ee[4][4];
#pragma unroll
            for (int j = 0; j < 4; j++)
#pragma unroll
                for (int r = 0; r < 4; r++) ee[j][r] = __expf(sc[j][r]);
            if (diag) {
#pragma unroll
                for (int j = 0; j < 4; j++) {
                    const int sg = s0 + j * 16 + low;
#pragma unroll
                    for (int r = 0; r < 4; r++)
                        if (sg > l0t + wave * 16 + quad * 4 + r) ee[j][r] = 1.0f;
                }
            }
#pragma unroll
            for (int j = 0; j < 4; j++)
#pragma unroll
                for (int r = 0; r < 4; r++)
                    Ps[wave * 16 + quad * 4 + r][j * 16 + low] = f2bf(ee[j][r]);

            s16x8 pa0 = *(const s16x8*)&Ps[wave * 16 + low][quad * 8];
            s16x8 pa1 = *(const s16x8*)&Ps[wave * 16 + low][32 + quad * 8];
            sum = __builtin_amdgcn_mfma_f32_16x16x32_bf16(pa0, onesv, sum, 0, 0, 0);
            sum = __builtin_amdgcn_mfma_f32_16x16x32_bf16(pa1, onesv, sum, 0, 0, 0);
#pragma unroll
            for (int n = 0; n < 4; n++) {
                s16x8 bv0 = *(const s16x8*)&Vs[n * 16 + low][quad * 8];
                s16x8 bv1 = *(const s16x8*)&Vs[n * 16 + low][32 + quad * 8];
                acc[n] = __builtin_amdgcn_mfma_f32_16x16x32_bf16(pa0, bv0, acc[n], 0, 0, 0);
                acc[n] = __builtin_amdgcn_mfma_f32_16x16x32_bf16(pa1, bv1, acc[n], 0, 0, 0);
            }
        };

        tilework(aqB0, aqB1, accB, sumB, l0B, c == tB);
        if (c <= tA) tilework(aqA0, aqA1, accA, sumA, l0A, c == tA);
    }

    auto finalize = [&](f32x4* acc, f32x4 sum, int tt) {
        const float tail = (float)(S_ - 64 * (tt + 1));
        const float* sufp = vsuf + ((size_t)bh * 33 + tt + 1) * 64;
        float sv[4];
#pragma unroll
        for (int n = 0; n < 4; n++) sv[n] = sufp[n * 16 + low];
#pragma unroll
        for (int r = 0; r < 4; r++) {
            float inv = 1.0f / (sum[r] + tail);   // sum[r]: row quad*4+r (ones-MFMA)
            int lg = tt * 64 + wave * 16 + quad * 4 + r;
            size_t base = ((size_t)b * S_ + lg) * D_ + h * HD_;
#pragma unroll
            for (int n = 0; n < 4; n++)
                ao[base + n * 16 + low] = f2bf((acc[n][r] + sv[n]) * inv);
        }
    };
    finalize(accA, sumA, tA);
    finalize(accB, sumB, tB);
}

// ---------------- launch ----------------
extern "C" void kernel_launch(void* const* d_in, const int* in_sizes, int n_in,
                              void* d_out, int out_size, void* d_ws, size_t ws_size,
                              hipStream_t stream) {
    const float* q  = (const float*)d_in[0];
    const float* k  = (const float*)d_in[1];
    const float* v  = (const float*)d_in[2];
    const float* Wq = (const float*)d_in[4];
    const float* Wk = (const float*)d_in[5];
    const float* Wv = (const float*)d_in[6];
    const float* Wo = (const float*)d_in[7];
    const float* bo = (const float*)d_in[8];

    char* ws = (char*)d_ws;
    const size_t SZX = (size_t)B_ * S_ * D_ * 2;
    const size_t SZW = (size_t)D_ * D_ * 2;

    unsigned short* qb   = (unsigned short*)(ws);
    unsigned short* kb   = (unsigned short*)(ws + SZX);
    unsigned short* vb   = (unsigned short*)(ws + 2 * SZX);
    unsigned short* qhp  = (unsigned short*)(ws + 3 * SZX);
    unsigned short* khp  = (unsigned short*)(ws + 4 * SZX);
    unsigned short* vhTp = (unsigned short*)(ws + 5 * SZX);
    unsigned short* Wqb  = (unsigned short*)(ws + 6 * SZX);
    unsigned short* Wkb  = (unsigned short*)(ws + 6 * SZX + SZW);
    unsigned short* Wvb  = (unsigned short*)(ws + 6 * SZX + 2 * SZW);
    unsigned short* Wob  = (unsigned short*)(ws + 6 * SZX + 3 * SZW);
    unsigned short* aop  = qb;              // qb dead after Q projection
    float*          vsuf = (float*)vb;      // vb dead after V projection

    static bool s_init = false;
    if (!s_init) {
        hipFuncSetAttribute((const void*)gemm_qkv8,
                            hipFuncAttributeMaxDynamicSharedMemorySize, 98304);
        hipFuncSetAttribute((const void*)gemm_wo8,
                            hipFuncAttributeMaxDynamicSharedMemorySize, 98304);
        s_init = true;
    }

    cvt_all<<<(3 * (1 << 21) + 4 * (1 << 18)) / 256, 256, 0, stream>>>(
        q, k, v, Wq, Wk, Wv, Wo, qb, kb, vb, Wqb, Wkb, Wvb, Wob);

    gemm_qkv8<<<768, 512, 98304, stream>>>(qb, kb, vb, Wqb, Wkb, Wvb, qhp, khp, vhTp);

    vsuffix_kernel<<<1024, 256, 0, stream>>>(vhTp, vsuf);
    attn_kernel<<<1024, 256, 0, stream>>>(qhp, khp, vhTp, vsuf, aop);

    gemm_wo8<<<256, 512, 98304, stream>>>(aop, Wob, (float*)d_out, bo);
}